// Round 1
// baseline (64.248 us; speedup 1.0000x reference)
//
#include <hip/hip_runtime.h>
#include <hip/hip_bf16.h>
#include <math.h>

// Problem constants (from reference)
#define BB 32
#define CC 30
#define RR 196
#define DD 256
#define KK 20
#define GG 14            // sqrt(RR)
#define CONF_ 0.5f
#define IOU_THR_ 0.3f

constexpr int NROWS = BB * CC * RR;          // 188160
constexpr int COORDS_OFF = 0;                // (B,C,K,4) = 76800
constexpr int PROBS_OFF  = BB * CC * KK * 4; // 76800
constexpr int KEEP_OFF   = PROBS_OFF + BB * CC * KK;  // 96000
constexpr int PRES_OFF   = KEEP_OFF + BB * CC * KK;   // 115200

// ---------------------------------------------------------------------------
// Stage 1: presence logits for every row. One wave per row per iteration.
// Each lane loads one float4 (lane*16B) -> the wave covers the full 256-float
// row with a single coalesced 1 KiB transaction burst. Memory-bound.
// ---------------------------------------------------------------------------
__global__ __launch_bounds__(256) void presence_kernel(
    const float4* __restrict__ lf,        // NROWS * 64 float4
    const float*  __restrict__ W_pres,    // 256
    const float*  __restrict__ b_pres,    // 1
    float*        __restrict__ presence_out)  // NROWS
{
    const int lane  = threadIdx.x & 63;
    const int wave  = blockIdx.x * (blockDim.x >> 6) + (threadIdx.x >> 6);
    const int nwave = gridDim.x * (blockDim.x >> 6);

    const float4 w = reinterpret_cast<const float4*>(W_pres)[lane];
    const float  bp = b_pres[0];

    for (int row = wave; row < NROWS; row += nwave) {
        const float4 x = lf[(size_t)row * 64 + lane];
        float p = x.x * w.x + x.y * w.y + x.z * w.z + x.w * w.w;
        #pragma unroll
        for (int off = 32; off; off >>= 1) p += __shfl_xor(p, off);
        if (lane == 0) presence_out[row] = p + bp;
    }
}

// ---------------------------------------------------------------------------
// Stage 2: per (b,c): top-K on logits (monotone sigmoid), recompute coords for
// the K selected rows only, grid-center add, NMS, write outputs.
// One 64-lane block per (b,c); 960 blocks total. Tiny.
// ---------------------------------------------------------------------------
__global__ __launch_bounds__(64) void topk_nms_kernel(
    const float4* __restrict__ lf,
    const float*  __restrict__ W_coords,  // 4 x 256
    const float*  __restrict__ b_coords,  // 4
    const float*  __restrict__ presence,  // NROWS logits (in d_out)
    float*        __restrict__ coords_out,
    float*        __restrict__ probs_out,
    float*        __restrict__ keep_out)
{
    const int bc   = blockIdx.x;      // b*CC + c
    const int lane = threadIdx.x;

    __shared__ float s_topv[KK];
    __shared__ int   s_topi[KK];
    __shared__ float s_box[KK][4];

    // --- load the 196 logits: 4 per lane (padded with -inf) ---
    const float* pres = presence + (size_t)bc * RR;
    float v[4]; int id[4];
    #pragma unroll
    for (int t = 0; t < 4; ++t) {
        const int r = lane + 64 * t;
        id[t] = r;
        v[t]  = (r < RR) ? pres[r] : -1e30f;
    }

    // --- top-K selection: K sequential wave-argmax reductions ---
    for (int k = 0; k < KK; ++k) {
        float bv = v[0]; int bi = id[0];
        #pragma unroll
        for (int t = 1; t < 4; ++t)
            if (v[t] > bv || (v[t] == bv && id[t] < bi)) { bv = v[t]; bi = id[t]; }
        #pragma unroll
        for (int off = 32; off; off >>= 1) {
            const float ov = __shfl_xor(bv, off);
            const int   oi = __shfl_xor(bi, off);
            if (ov > bv || (ov == bv && oi < bi)) { bv = ov; bi = oi; }
        }
        // mark taken (all lanes agree on bi; owner invalidates its copy)
        #pragma unroll
        for (int t = 0; t < 4; ++t)
            if (id[t] == bi) v[t] = -1e30f;
        if (lane == 0) { s_topv[k] = bv; s_topi[k] = bi; }
    }
    __syncthreads();

    // --- recompute coords for the K selected rows ---
    float4 wc[4];
    #pragma unroll
    for (int o = 0; o < 4; ++o)
        wc[o] = reinterpret_cast<const float4*>(W_coords + o * DD)[lane];

    for (int k = 0; k < KK; ++k) {
        const int row = s_topi[k];
        const float4 x = lf[((size_t)bc * RR + row) * 64 + lane];
        float acc[4];
        #pragma unroll
        for (int o = 0; o < 4; ++o)
            acc[o] = x.x * wc[o].x + x.y * wc[o].y + x.z * wc[o].z + x.w * wc[o].w;
        #pragma unroll
        for (int off = 32; off; off >>= 1) {
            #pragma unroll
            for (int o = 0; o < 4; ++o) acc[o] += __shfl_xor(acc[o], off);
        }
        if (lane == 0) {
            const int   ix = row % GG, iy = row / GG;
            const float cx = (ix + 0.5f) / (float)GG;
            const float cy = (iy + 0.5f) / (float)GG;
            s_box[k][0] = acc[0] + b_coords[0] + cx;
            s_box[k][1] = acc[1] + b_coords[1] + cy;
            s_box[k][2] = acc[2] + b_coords[2] + cx;
            s_box[k][3] = acc[3] + b_coords[3] + cy;
        }
    }
    __syncthreads();

    // --- NMS: lane j owns box j (j < KK). Sequential over i, lockstep wave ---
    float x1 = 0.f, y1 = 0.f, x2 = 0.f, y2 = 0.f, area = 0.f, prob = 0.f;
    int kp = 0;
    if (lane < KK) {
        x1 = s_box[lane][0]; y1 = s_box[lane][1];
        x2 = s_box[lane][2]; y2 = s_box[lane][3];
        area = fmaxf(x2 - x1, 0.f) * fmaxf(y2 - y1, 0.f);
        prob = 1.f / (1.f + expf(-s_topv[lane]));
        kp = (prob > CONF_) ? 1 : 0;
    }
    for (int i = 0; i < KK; ++i) {
        const int   ki  = __shfl(kp, i);     // keep[i] at iteration i (lockstep)
        const float bx1 = __shfl(x1, i), by1 = __shfl(y1, i);
        const float bx2 = __shfl(x2, i), by2 = __shfl(y2, i);
        const float ai  = __shfl(area, i);
        if (lane > i && lane < KK && ki) {
            const float xx1 = fmaxf(x1, bx1), yy1 = fmaxf(y1, by1);
            const float xx2 = fminf(x2, bx2), yy2 = fminf(y2, by2);
            const float inter = fmaxf(xx2 - xx1, 0.f) * fmaxf(yy2 - yy1, 0.f);
            const float uni   = area + ai - inter;
            const float iou   = inter / fmaxf(uni, 1e-9f);
            if (iou > IOU_THR_) kp = 0;
        }
    }

    // --- write outputs ---
    if (lane < KK) {
        const size_t base = (size_t)bc * KK + lane;
        const float  kf   = kp ? 1.f : 0.f;
        coords_out[base * 4 + 0] = x1 * kf;
        coords_out[base * 4 + 1] = y1 * kf;
        coords_out[base * 4 + 2] = x2 * kf;
        coords_out[base * 4 + 3] = y2 * kf;
        probs_out[base] = prob * kf;
        keep_out[base]  = kf;
    }
}

extern "C" void kernel_launch(void* const* d_in, const int* in_sizes, int n_in,
                              void* d_out, int out_size, void* d_ws, size_t ws_size,
                              hipStream_t stream) {
    const float* lf       = (const float*)d_in[0];
    const float* W_coords = (const float*)d_in[1];
    const float* b_coords = (const float*)d_in[2];
    const float* W_pres   = (const float*)d_in[3];
    const float* b_pres   = (const float*)d_in[4];

    float* out         = (float*)d_out;
    float* coords_out  = out + COORDS_OFF;
    float* probs_out   = out + PROBS_OFF;
    float* keep_out    = out + KEEP_OFF;
    float* presence_out= out + PRES_OFF;

    // Stage 1: 2048 blocks x 256 threads = 8192 waves, grid-stride over rows.
    presence_kernel<<<2048, 256, 0, stream>>>(
        (const float4*)lf, W_pres, b_pres, presence_out);

    // Stage 2: one 64-lane block per (b,c).
    topk_nms_kernel<<<BB * CC, 64, 0, stream>>>(
        (const float4*)lf, W_coords, b_coords, presence_out,
        coords_out, probs_out, keep_out);
}

// Round 2
// 52.778 us; speedup vs baseline: 1.2173x; 1.2173x over previous
//
#include <hip/hip_runtime.h>
#include <hip/hip_bf16.h>
#include <math.h>

// Problem constants (from reference)
#define BB 32
#define CC 30
#define RR 196
#define DD 256
#define KK 20
#define GG 14            // sqrt(RR)
#define CONF_ 0.5f
#define IOU_THR_ 0.3f

constexpr int NROWS = BB * CC * RR;          // 188160
constexpr int COORDS_OFF = 0;                // (B,C,K,4) = 76800
constexpr int PROBS_OFF  = BB * CC * KK * 4; // 76800
constexpr int KEEP_OFF   = PROBS_OFF + BB * CC * KK;  // 96000
constexpr int PRES_OFF   = KEEP_OFF + BB * CC * KK;   // 115200

// ---------------------------------------------------------------------------
// Stage 1: presence logits. 16 rows per wave, 4 lanes per row.
// Each lane: 16 independent float4 loads (16 KiB in flight per wave-iter),
// 4 FMAs each; reduction = 2 shuffles per 16 rows (vs 6 per row before).
// Rows per block (4 waves): 64. Grid = NROWS/64 = 2940 blocks, no loop.
// ---------------------------------------------------------------------------
__global__ __launch_bounds__(256) void presence_kernel(
    const float4* __restrict__ lf,        // NROWS * 64 float4
    const float*  __restrict__ W_pres,    // 256
    const float*  __restrict__ b_pres,    // 1
    float*        __restrict__ presence_out)  // NROWS
{
    const int lane = threadIdx.x & 63;
    const int wave = blockIdx.x * 4 + (threadIdx.x >> 6);
    const int sub  = lane >> 2;           // row within 16-row group
    const int q    = lane & 3;            // quarter-row (16 floats each... x4 lanes)

    const int row  = wave * 16 + sub;     // always < NROWS (exact grid)
    const float4* __restrict__ rowp = lf + (size_t)row * 64 + q;
    const float4* __restrict__ wp   = reinterpret_cast<const float4*>(W_pres) + q;

    float p = 0.f;
    #pragma unroll
    for (int t = 0; t < 16; ++t) {
        const float4 x = rowp[4 * t];
        const float4 w = wp[4 * t];
        p += x.x * w.x + x.y * w.y + x.z * w.z + x.w * w.w;
    }
    p += __shfl_xor(p, 1);
    p += __shfl_xor(p, 2);
    if (q == 0) presence_out[row] = p + b_pres[0];
}

// ---------------------------------------------------------------------------
// Stage 2: per (b,c): top-K on logits (monotone sigmoid), recompute coords for
// the K selected rows (4 rows in parallel, 16 lanes/row, unrolled -> loads
// overlap), grid-center add, NMS, write outputs. One wave per (b,c).
// ---------------------------------------------------------------------------
__global__ __launch_bounds__(64) void topk_nms_kernel(
    const float4* __restrict__ lf,
    const float*  __restrict__ W_coords,  // 4 x 256
    const float*  __restrict__ b_coords,  // 4
    const float*  __restrict__ presence,  // NROWS logits (in d_out)
    float*        __restrict__ coords_out,
    float*        __restrict__ probs_out,
    float*        __restrict__ keep_out)
{
    const int bc   = blockIdx.x;      // b*CC + c
    const int lane = threadIdx.x;

    __shared__ float s_topv[KK];
    __shared__ int   s_topi[KK];
    __shared__ float s_box[KK][4];

    // --- load the 196 logits: 4 per lane (padded with -inf) ---
    const float* pres = presence + (size_t)bc * RR;
    float v[4]; int id[4];
    #pragma unroll
    for (int t = 0; t < 4; ++t) {
        const int r = lane + 64 * t;
        id[t] = r;
        v[t]  = (r < RR) ? pres[r] : -1e30f;
    }

    // --- top-K selection: K sequential wave-argmax reductions ---
    for (int k = 0; k < KK; ++k) {
        float bv = v[0]; int bi = id[0];
        #pragma unroll
        for (int t = 1; t < 4; ++t)
            if (v[t] > bv || (v[t] == bv && id[t] < bi)) { bv = v[t]; bi = id[t]; }
        #pragma unroll
        for (int off = 32; off; off >>= 1) {
            const float ov = __shfl_xor(bv, off);
            const int   oi = __shfl_xor(bi, off);
            if (ov > bv || (ov == bv && oi < bi)) { bv = ov; bi = oi; }
        }
        #pragma unroll
        for (int t = 0; t < 4; ++t)
            if (id[t] == bi) v[t] = -1e30f;
        if (lane == 0) { s_topv[k] = bv; s_topi[k] = bi; }
    }
    __syncthreads();

    // --- coords for the K selected rows: 4 rows per pass, 16 lanes/row ---
    const int g  = lane >> 4;   // which of the 4 rows this lane works on
    const int sl = lane & 15;   // sub-lane within the row

    float4 wc[4][4];
    #pragma unroll
    for (int o = 0; o < 4; ++o)
        #pragma unroll
        for (int t = 0; t < 4; ++t)
            wc[o][t] = reinterpret_cast<const float4*>(W_coords + o * DD)[sl + 16 * t];

    #pragma unroll
    for (int it = 0; it < KK / 4; ++it) {
        const int k   = it * 4 + g;
        const int row = s_topi[k];
        const float4* __restrict__ rp = lf + ((size_t)bc * RR + row) * 64 + sl;
        float acc[4] = {0.f, 0.f, 0.f, 0.f};
        #pragma unroll
        for (int t = 0; t < 4; ++t) {
            const float4 x = rp[16 * t];
            #pragma unroll
            for (int o = 0; o < 4; ++o)
                acc[o] += x.x * wc[o][t].x + x.y * wc[o][t].y
                        + x.z * wc[o][t].z + x.w * wc[o][t].w;
        }
        #pragma unroll
        for (int off = 8; off; off >>= 1) {
            #pragma unroll
            for (int o = 0; o < 4; ++o) acc[o] += __shfl_xor(acc[o], off);
        }
        if (sl == 0) {
            const int   ix = row % GG, iy = row / GG;
            const float cx = (ix + 0.5f) / (float)GG;
            const float cy = (iy + 0.5f) / (float)GG;
            s_box[k][0] = acc[0] + b_coords[0] + cx;
            s_box[k][1] = acc[1] + b_coords[1] + cy;
            s_box[k][2] = acc[2] + b_coords[2] + cx;
            s_box[k][3] = acc[3] + b_coords[3] + cy;
        }
    }
    __syncthreads();

    // --- NMS: lane j owns box j (j < KK). Sequential over i, lockstep wave ---
    float x1 = 0.f, y1 = 0.f, x2 = 0.f, y2 = 0.f, area = 0.f, prob = 0.f;
    int kp = 0;
    if (lane < KK) {
        x1 = s_box[lane][0]; y1 = s_box[lane][1];
        x2 = s_box[lane][2]; y2 = s_box[lane][3];
        area = fmaxf(x2 - x1, 0.f) * fmaxf(y2 - y1, 0.f);
        prob = 1.f / (1.f + expf(-s_topv[lane]));
        kp = (prob > CONF_) ? 1 : 0;
    }
    for (int i = 0; i < KK; ++i) {
        const int   ki  = __shfl(kp, i);
        const float bx1 = __shfl(x1, i), by1 = __shfl(y1, i);
        const float bx2 = __shfl(x2, i), by2 = __shfl(y2, i);
        const float ai  = __shfl(area, i);
        if (lane > i && lane < KK && ki) {
            const float xx1 = fmaxf(x1, bx1), yy1 = fmaxf(y1, by1);
            const float xx2 = fminf(x2, bx2), yy2 = fminf(y2, by2);
            const float inter = fmaxf(xx2 - xx1, 0.f) * fmaxf(yy2 - yy1, 0.f);
            const float uni   = area + ai - inter;
            const float iou   = inter / fmaxf(uni, 1e-9f);
            if (iou > IOU_THR_) kp = 0;
        }
    }

    // --- write outputs ---
    if (lane < KK) {
        const size_t base = (size_t)bc * KK + lane;
        const float  kf   = kp ? 1.f : 0.f;
        coords_out[base * 4 + 0] = x1 * kf;
        coords_out[base * 4 + 1] = y1 * kf;
        coords_out[base * 4 + 2] = x2 * kf;
        coords_out[base * 4 + 3] = y2 * kf;
        probs_out[base] = prob * kf;
        keep_out[base]  = kf;
    }
}

extern "C" void kernel_launch(void* const* d_in, const int* in_sizes, int n_in,
                              void* d_out, int out_size, void* d_ws, size_t ws_size,
                              hipStream_t stream) {
    const float* lf       = (const float*)d_in[0];
    const float* W_coords = (const float*)d_in[1];
    const float* b_coords = (const float*)d_in[2];
    const float* W_pres   = (const float*)d_in[3];
    const float* b_pres   = (const float*)d_in[4];

    float* out          = (float*)d_out;
    float* coords_out   = out + COORDS_OFF;
    float* probs_out    = out + PROBS_OFF;
    float* keep_out     = out + KEEP_OFF;
    float* presence_out = out + PRES_OFF;

    // Stage 1: 2940 blocks x 4 waves, 16 rows/wave -> exactly NROWS rows.
    presence_kernel<<<NROWS / 64, 256, 0, stream>>>(
        (const float4*)lf, W_pres, b_pres, presence_out);

    // Stage 2: one 64-lane block per (b,c).
    topk_nms_kernel<<<BB * CC, 64, 0, stream>>>(
        (const float4*)lf, W_coords, b_coords, presence_out,
        coords_out, probs_out, keep_out);
}